// Round 7
// baseline (194.191 us; speedup 1.0000x reference)
//
#include <hip/hip_runtime.h>
#include <math.h>

// BioREDirect, SINGLE fused launch: 228 blocks x 1024 threads.
//   blocks 0..191  (producer): online-softmax ragged attention-pool for (b,g)
//       -> Pbf[g][b][768] (bf16, ws); b==0 blocks bias-init out[]; then
//       device-scope release + flags[g]++ (CAS poison->0 first).
//   blocks 192..227 (consumer): 12 i-tiles x 3 groups. Prefetch W f32->bf16
//       (k<384 into LDS, k>=384 into regs) CONCURRENTLY with producers; spin
//       on flags[g]==64 (acquire, agent scope); 24 MFMA steps (16x16x32 bf16);
//       tanh+bias epilogue -> LDS; classifier partials atomicAdd'ed into out.
// Co-residency: 228 blocks <= 256 CUs, <=128 VGPR, 50KB LDS -> no deadlock
// regardless of dispatch order. NOTE: ~150us of timed iteration is harness
// restore/poison fills (fixed, outside our control).

#define Hdim 768
#define Kdim 64
#define Sdim 512
#define Bdim 64
#define NPROD 192
#define POISON 0xAAAAAAAAu
#define WLD 392   // LDS row stride (ushorts) for k<384 W tile: 2-way banks, 16B aligned

typedef float f32x4 __attribute__((ext_vector_type(4)));
typedef short bf16x8 __attribute__((ext_vector_type(8)));

__device__ __forceinline__ unsigned short f2bf(float f) {
    union { float f; unsigned int u; } c; c.f = f;
    unsigned int u = c.u + 0x7FFFu + ((c.u >> 16) & 1u);  // RNE
    return (unsigned short)(u >> 16);
}

__global__ __launch_bounds__(1024) void biored_all(
    const float* __restrict__ seq,
    const int* __restrict__ idxr, const int* __restrict__ lenr,
    const int* __restrict__ idxn, const int* __restrict__ lenn,
    const int* __restrict__ idxd, const int* __restrict__ lend,
    const float* __restrict__ cbr, const float* __restrict__ cbn,
    const float* __restrict__ cbd,
    const float* __restrict__ dWr, const float* __restrict__ dWn,
    const float* __restrict__ dWd,
    const float* __restrict__ dbr, const float* __restrict__ dbn,
    const float* __restrict__ dbd,
    const float* __restrict__ cWr, const float* __restrict__ cWn,
    const float* __restrict__ cWd,
    unsigned short* __restrict__ Pbf,   // ws: [3][64][768] bf16
    unsigned int* __restrict__ flags,   // ws: [3], poisoned 0xAA
    float* __restrict__ out)
{
    __shared__ __align__(16) char smem[50432];
    const int tid = threadIdx.x, lane = tid & 63, wv = tid >> 6;
    const int bid = blockIdx.x;

    if (bid < NPROD) {
        // ================= PRODUCER: attention pooling =================
        const int b = bid & 63, g = bid >> 6;
        const int* idxp = (g == 0) ? idxr : (g == 1) ? idxn : idxd;
        const int* lnp  = (g == 0) ? lenr : (g == 1) ? lenn : lend;

        int*   sidx = (int*)smem;                          // 64
        float* wm   = (float*)(smem + 256);                // 16
        float* wl   = (float*)(smem + 320);                // 16
        float* coef = (float*)(smem + 384);                // 16
        float (*wpart)[Hdim] = (float (*)[Hdim])(smem + 448);  // 16x768 f32

        if (tid < Kdim) sidx[tid] = idxp[b * Kdim + tid];
        const int len = lnp[b];

        if (b == 0) {  // bias-init of out, released with the flag
            if (g == 0)      { if (tid < 576) out[tid]       = cbr[tid % 9]; }
            else if (g == 1) { if (tid < 192) out[576 + tid] = cbn[tid % 3]; }
            else             { if (tid < 192) out[768 + tid] = cbd[tid % 3]; }
        }
        __syncthreads();

        unsigned short* Pb = Pbf + ((size_t)g * Bdim + b) * Hdim;

        if (len > 0) {
            const float* row0 = seq + ((size_t)b * Sdim + sidx[0]) * Hdim;
            float g0[12];
#pragma unroll
            for (int k = 0; k < 3; ++k) {
                float4 v = *(const float4*)(row0 + 4 * lane + 256 * k);
                g0[4 * k + 0] = v.x; g0[4 * k + 1] = v.y;
                g0[4 * k + 2] = v.z; g0[4 * k + 3] = v.w;
            }
            float m = -1e30f, l = 0.f;
            float p[12] = {0,0,0,0,0,0,0,0,0,0,0,0};

            for (int j = wv; j < len; j += 16) {
                const float* rowj = seq + ((size_t)b * Sdim + sidx[j]) * Hdim;
                float v[12];
#pragma unroll
                for (int k = 0; k < 3; ++k) {
                    float4 t = *(const float4*)(rowj + 4 * lane + 256 * k);
                    v[4 * k + 0] = t.x; v[4 * k + 1] = t.y;
                    v[4 * k + 2] = t.z; v[4 * k + 3] = t.w;
                }
                float s = 0.f;
#pragma unroll
                for (int k = 0; k < 12; ++k) s += g0[k] * v[k];
#pragma unroll
                for (int off = 32; off > 0; off >>= 1) s += __shfl_xor(s, off, 64);

                float mn    = fmaxf(m, s);
                float scale = __expf(m - mn);
                float e     = __expf(s - mn);
                l = l * scale + e;
#pragma unroll
                for (int k = 0; k < 12; ++k) p[k] = p[k] * scale + e * v[k];
                m = mn;
            }

            if (lane == 0) { wm[wv] = m; wl[wv] = l; }
#pragma unroll
            for (int k = 0; k < 3; ++k)
                *(float4*)&wpart[wv][4 * lane + 256 * k] =
                    make_float4(p[4 * k], p[4 * k + 1], p[4 * k + 2], p[4 * k + 3]);
            __syncthreads();

            if (wv == 0 && lane < 16) {
                float mw = wm[lane], lw = wl[lane];
                float M = mw;
#pragma unroll
                for (int off = 8; off > 0; off >>= 1) M = fmaxf(M, __shfl_xor(M, off, 64));
                float sc = __expf(mw - M);     // 0 for waves with no j
                float Ls = lw * sc;
#pragma unroll
                for (int off = 8; off > 0; off >>= 1) Ls += __shfl_xor(Ls, off, 64);
                coef[lane] = sc / Ls;
            }
            __syncthreads();

            if (tid < Hdim) {
                float acc = 0.f;
#pragma unroll
                for (int w = 0; w < 16; ++w) acc += wpart[w][tid] * coef[w];
                Pb[tid] = f2bf(acc);
            }
        } else {
            if (tid < Hdim) Pb[tid] = f2bf(seq[(size_t)b * Sdim * Hdim + tid]);
        }

        __syncthreads();   // all stores issued & drained (barrier implies vmcnt(0))
        if (tid == 0) {
            __threadfence();                       // agent-release: L2 writeback
            atomicCAS(&flags[g], POISON, 0u);      // first toucher clears poison
            atomicAdd(&flags[g], 1u);
        }
    } else {
        // ================= CONSUMER: dense + tanh + classifier =================
        const int cid = bid - NPROD;
        const int g = cid / 12, mt = cid % 12;
        const float* dW = (g == 0) ? dWr : (g == 1) ? dWn : dWd;
        const float* db = (g == 0) ? dbr : (g == 1) ? dbn : dbd;
        const float* cW = (g == 0) ? cWr : (g == 1) ? cWn : cWd;
        const int nlab = (g == 0) ? 9 : 3;
        const int off  = (g == 0) ? 0 : (g == 1) ? 576 : 768;
        const int i0 = mt * 64;
        const int q = lane >> 4, col = lane & 15;

        unsigned short* Wlds = (unsigned short*)smem;   // [64][WLD], k<384

        // phase 1a: stage W[:, 0:384) -> LDS bf16 (all 16 waves; P-independent)
#pragma unroll
        for (int rr = 0; rr < 4; ++rr) {
            int row = wv * 4 + rr;
            const float* src = dW + (size_t)(i0 + row) * Hdim;
            {
                int k = lane * 4;
                float4 x = *(const float4*)(src + k);
                *(ushort4*)&Wlds[row * WLD + k] =
                    make_ushort4(f2bf(x.x), f2bf(x.y), f2bf(x.z), f2bf(x.w));
            }
            if (lane < 32) {
                int k = 256 + lane * 4;
                float4 x = *(const float4*)(src + k);
                *(ushort4*)&Wlds[row * WLD + k] =
                    make_ushort4(f2bf(x.x), f2bf(x.y), f2bf(x.z), f2bf(x.w));
            }
        }
        // phase 1b: waves 0..3 preload W[:, 384:768) A-frags into registers
        bf16x8 afrag[12];
        if (wv < 4) {
            const float* Arow = dW + (size_t)(i0 + wv * 16 + col) * Hdim + 384 + 8 * q;
#pragma unroll
            for (int t = 0; t < 12; ++t) {
                float4 x = *(const float4*)(Arow + t * 32);
                float4 y = *(const float4*)(Arow + t * 32 + 4);
                bf16x8 a;
                a[0] = (short)f2bf(x.x); a[1] = (short)f2bf(x.y);
                a[2] = (short)f2bf(x.z); a[3] = (short)f2bf(x.w);
                a[4] = (short)f2bf(y.x); a[5] = (short)f2bf(y.y);
                a[6] = (short)f2bf(y.z); a[7] = (short)f2bf(y.w);
                afrag[t] = a;
            }
        }

        // phase 2: wait for all 64 producers of this group (acquire, agent)
        if (tid == 0) {
            while (__hip_atomic_load(&flags[g], __ATOMIC_ACQUIRE,
                                     __HIP_MEMORY_SCOPE_AGENT) != 64u)
                __builtin_amdgcn_s_sleep(8);
        }
        __syncthreads();

        // phase 3: MFMA K-loop
        f32x4 acc[4] = {{0,0,0,0},{0,0,0,0},{0,0,0,0},{0,0,0,0}};
        if (wv < 4) {
            const unsigned short* Bp = Pbf + ((size_t)g * Bdim + col) * Hdim + 8 * q;
#pragma unroll
            for (int s = 0; s < 12; ++s) {
                bf16x8 a = *(const bf16x8*)&Wlds[(wv * 16 + col) * WLD + s * 32 + 8 * q];
#pragma unroll
                for (int n = 0; n < 4; ++n) {
                    bf16x8 bb = *(const bf16x8*)(Bp + (size_t)n * 16 * Hdim + s * 32);
                    acc[n] = __builtin_amdgcn_mfma_f32_16x16x32_bf16(a, bb, acc[n], 0, 0, 0);
                }
            }
#pragma unroll
            for (int t = 0; t < 12; ++t) {
#pragma unroll
                for (int n = 0; n < 4; ++n) {
                    bf16x8 bb = *(const bf16x8*)(Bp + (size_t)n * 16 * Hdim + 384 + t * 32);
                    acc[n] = __builtin_amdgcn_mfma_f32_16x16x32_bf16(afrag[t], bb, acc[n], 0, 0, 0);
                }
            }
        }
        __syncthreads();   // Wlds reads done -> safe to alias hs over it

        float (*hs)[65] = (float (*)[65])smem;
        if (wv < 4) {
#pragma unroll
            for (int n = 0; n < 4; ++n) {
                int bb = n * 16 + col;
#pragma unroll
                for (int r = 0; r < 4; ++r) {
                    int il = wv * 16 + q * 4 + r;
                    hs[il][bb] = tanhf(acc[n][r] + db[i0 + il]);
                }
            }
        }
        __syncthreads();

        if (wv < 4) {
            for (int c = wv; c < nlab; c += 4) {
                const float* wr = cW + (size_t)c * Hdim + i0;
                float a = 0.f;
#pragma unroll 16
                for (int il = 0; il < 64; ++il)
                    a += wr[il] * hs[il][lane];
                atomicAdd(&out[off + lane * nlab + c], a);
            }
        }
    }
}

extern "C" void kernel_launch(void* const* d_in, const int* in_sizes, int n_in,
                              void* d_out, int out_size, void* d_ws, size_t ws_size,
                              hipStream_t stream) {
    const float* seq  = (const float*)d_in[0];
    const int*   idxr = (const int*)d_in[1];
    const int*   lenr = (const int*)d_in[2];
    const int*   idxn = (const int*)d_in[3];
    const int*   lenn = (const int*)d_in[4];
    const int*   idxd = (const int*)d_in[5];
    const int*   lend = (const int*)d_in[6];
    const float* dWr  = (const float*)d_in[7];
    const float* dbr  = (const float*)d_in[8];
    const float* cWr  = (const float*)d_in[9];
    const float* cbr  = (const float*)d_in[10];
    const float* dWn  = (const float*)d_in[11];
    const float* dbn  = (const float*)d_in[12];
    const float* cWn  = (const float*)d_in[13];
    const float* cbn  = (const float*)d_in[14];
    const float* dWd  = (const float*)d_in[15];
    const float* dbd  = (const float*)d_in[16];
    const float* cWd  = (const float*)d_in[17];
    const float* cbd  = (const float*)d_in[18];
    float* out = (float*)d_out;

    unsigned short* Pbf  = (unsigned short*)d_ws;               // 3*64*768 bf16
    unsigned int*   flags = (unsigned int*)((char*)d_ws + (size_t)3 * Bdim * Hdim * 2);

    biored_all<<<NPROD + 36, 1024, 0, stream>>>(
        seq, idxr, lenr, idxn, lenn, idxd, lend,
        cbr, cbn, cbd, dWr, dWn, dWd, dbr, dbn, dbd, cWr, cWn, cWd,
        Pbf, flags, out);
}

// Round 8
// 192.077 us; speedup vs baseline: 1.0110x; 1.0110x over previous
//
#include <hip/hip_runtime.h>
#include <math.h>

// BioREDirect, 2-kernel (R5 structure, best: 189us), K1 j-loop fully unrolled.
// K1 (1024 thr, 192 blocks): attention-pool; each wave owns <=4 j's, ALL row
//     loads issued up front (no serial HBM round-trips), interleaved butterfly
//     reduces, single non-chained softmax accumulate -> Pbf (bf16). Tail:
//     bulk W f32->bf16 convert -> Wbf; b==0 blocks bias-init out[].
// K2 (256 thr, 36 blocks): barrier-free MFMA dense+tanh, fragments direct from
//     global (bf16x8 = one dwordx4), classifier partials atomicAdd into out.
// NOTE: ~150us of the timed iteration is harness restore/poison fills (fixed).

#define Hdim 768
#define Kdim 64
#define Sdim 512
#define Bdim 64

typedef float f32x4 __attribute__((ext_vector_type(4)));
typedef short bf16x8 __attribute__((ext_vector_type(8)));

__device__ __forceinline__ unsigned short f2bf(float f) {
    union { float f; unsigned int u; } c; c.f = f;
    unsigned int u = c.u + 0x7FFFu + ((c.u >> 16) & 1u);  // RNE
    return (unsigned short)(u >> 16);
}

__device__ __forceinline__ void cvt8(const float* __restrict__ src,
                                     unsigned short* __restrict__ dst) {
    float4 x = *(const float4*)src, y = *(const float4*)(src + 4);
    *(ushort4*)dst       = make_ushort4(f2bf(x.x), f2bf(x.y), f2bf(x.z), f2bf(x.w));
    *(ushort4*)(dst + 4) = make_ushort4(f2bf(y.x), f2bf(y.y), f2bf(y.z), f2bf(y.w));
}

// ---------------- K1: attention pooling, unrolled j (16 waves) ----------------
__global__ __launch_bounds__(1024) void k_pool(
    const float* __restrict__ seq,
    const int* __restrict__ idxr, const int* __restrict__ lenr,
    const int* __restrict__ idxn, const int* __restrict__ lenn,
    const int* __restrict__ idxd, const int* __restrict__ lend,
    const float* __restrict__ cbr, const float* __restrict__ cbn,
    const float* __restrict__ cbd,
    const float* __restrict__ dWr, const float* __restrict__ dWn,
    const float* __restrict__ dWd,
    unsigned short* __restrict__ Wbf,   // [3][768][768] bf16
    unsigned short* __restrict__ Pbf,   // [3][64][768]  bf16
    float* __restrict__ out)            // bias-init; K2 atomicAdds partials
{
    const int b = blockIdx.x, g = blockIdx.y;
    const int tid = threadIdx.x, lane = tid & 63, wave = tid >> 6;  // 16 waves

    const int* idxp = (g == 0) ? idxr : (g == 1) ? idxn : idxd;
    const int* lnp  = (g == 0) ? lenr : (g == 1) ? lenn : lend;

    __shared__ int   sidx[Kdim];
    __shared__ float wm[16], wl[16], coef[16];
    __shared__ float wpart[16][Hdim];   // 48 KB

    if (tid < Kdim) sidx[tid] = idxp[b * Kdim + tid];
    const int len = lnp[b];

    if (b == 0) {  // bias-init of out (stream-ordered before K2)
        if (g == 0)      { if (tid < 576) out[tid]       = cbr[tid % 9]; }
        else if (g == 1) { if (tid < 192) out[576 + tid] = cbn[tid % 3]; }
        else             { if (tid < 192) out[768 + tid] = cbd[tid % 3]; }
    }
    __syncthreads();

    unsigned short* Pb = Pbf + ((size_t)g * Bdim + b) * Hdim;

    if (len > 0) {
        const float* row0 = seq + ((size_t)b * Sdim + sidx[0]) * Hdim;
        float g0[12];
#pragma unroll
        for (int k = 0; k < 3; ++k) {
            float4 t = *(const float4*)(row0 + 4 * lane + 256 * k);
            g0[4 * k + 0] = t.x; g0[4 * k + 1] = t.y;
            g0[4 * k + 2] = t.z; g0[4 * k + 3] = t.w;
        }

        // all <=4 rows for this wave, loads issued together
        const float* rp[4];
#pragma unroll
        for (int t = 0; t < 4; ++t) {
            int j = wave + 16 * t;
            int jj = (j < len) ? j : 0;            // safe fallback addr
            rp[t] = seq + ((size_t)b * Sdim + sidx[jj]) * Hdim + 4 * lane;
        }
        float v[4][12];
#pragma unroll
        for (int t = 0; t < 4; ++t)
#pragma unroll
            for (int k = 0; k < 3; ++k) {
                float4 x = *(const float4*)(rp[t] + 256 * k);
                v[t][4 * k + 0] = x.x; v[t][4 * k + 1] = x.y;
                v[t][4 * k + 2] = x.z; v[t][4 * k + 3] = x.w;
            }

        float s[4];
#pragma unroll
        for (int t = 0; t < 4; ++t) {
            float a = 0.f;
#pragma unroll
            for (int k = 0; k < 12; ++k) a += g0[k] * v[t][k];
            s[t] = a;
        }
        // interleaved butterflies: 4-way ILP on the shuffle chain
#pragma unroll
        for (int off = 32; off > 0; off >>= 1)
#pragma unroll
            for (int t = 0; t < 4; ++t) s[t] += __shfl_xor(s[t], off, 64);

#pragma unroll
        for (int t = 0; t < 4; ++t)
            if (wave + 16 * t >= len) s[t] = -1e30f;   // wave-uniform mask

        float m = fmaxf(fmaxf(s[0], s[1]), fmaxf(s[2], s[3]));
        float e[4], l = 0.f;
#pragma unroll
        for (int t = 0; t < 4; ++t) {
            e[t] = (wave + 16 * t < len) ? __expf(s[t] - m) : 0.f;
            l += e[t];
        }
        float p[12];
#pragma unroll
        for (int k = 0; k < 12; ++k)
            p[k] = e[0] * v[0][k] + e[1] * v[1][k] + e[2] * v[2][k] + e[3] * v[3][k];

        if (lane == 0) { wm[wave] = m; wl[wave] = l; }
#pragma unroll
        for (int k = 0; k < 3; ++k)
            *(float4*)&wpart[wave][4 * lane + 256 * k] =
                make_float4(p[4 * k], p[4 * k + 1], p[4 * k + 2], p[4 * k + 3]);
        __syncthreads();

        if (wave == 0 && lane < 16) {
            float mw = wm[lane], lw = wl[lane];
            float M = mw;
#pragma unroll
            for (int off = 8; off > 0; off >>= 1) M = fmaxf(M, __shfl_xor(M, off, 64));
            float sc = __expf(mw - M);        // 0 for waves with no j (mw=-1e30)
            float Ls = lw * sc;
#pragma unroll
            for (int off = 8; off > 0; off >>= 1) Ls += __shfl_xor(Ls, off, 64);
            coef[lane] = sc / Ls;
        }
        __syncthreads();

        if (tid < Hdim) {
            float acc = 0.f;
#pragma unroll
            for (int w = 0; w < 16; ++w) acc += wpart[w][tid] * coef[w];
            Pb[tid] = f2bf(acc);
        }
    } else {
        if (tid < Hdim) Pb[tid] = f2bf(seq[(size_t)b * Sdim * Hdim + tid]);
    }

    // ---- bulk W -> bf16 convert for K2 (off the pooling critical path) ----
    {
        const float* dW = (g == 0) ? dWr : (g == 1) ? dWn : dWd;
        unsigned short* Wb = Wbf + (size_t)g * Hdim * Hdim;
        for (int e2 = (b * 1024 + tid) * 8; e2 < Hdim * Hdim; e2 += 64 * 1024 * 8)
            cvt8(dW + e2, Wb + e2);
    }
}

// ---------------- K2: barrier-free MFMA dense+tanh + fused classifier ----------------
__global__ __launch_bounds__(256) void k_dense_cls(
    const unsigned short* __restrict__ Wbf,   // [3][768][768] bf16
    const unsigned short* __restrict__ Pbf,   // [3][64][768]  bf16
    const float* __restrict__ dbr, const float* __restrict__ dbn,
    const float* __restrict__ dbd,
    const float* __restrict__ cWr, const float* __restrict__ cWn,
    const float* __restrict__ cWd,
    float* __restrict__ out)
{
    const int mt = blockIdx.x, g = blockIdx.y;
    const float *db, *cW; int nlab, off;
    if (g == 0)      { db = dbr; cW = cWr; nlab = 9; off = 0;   }
    else if (g == 1) { db = dbn; cW = cWn; nlab = 3; off = 576; }
    else             { db = dbd; cW = cWd; nlab = 3; off = 768; }
    const int i0 = mt * 64;

    const int tid = threadIdx.x, lane = tid & 63, wv = tid >> 6;
    const int q = lane >> 4, col = lane & 15;

    // A frag: W row (i0 + wv*16 + m), m = lane&15, k = ks + 8q + j (8 contiguous)
    const unsigned short* Ap = Wbf + ((size_t)g * Hdim + i0 + wv * 16 + col) * Hdim + 8 * q;
    // B frag: P row (n*16 + col), k = ks + 8q + j
    const unsigned short* Bp = Pbf + ((size_t)g * Bdim + col) * Hdim + 8 * q;

    f32x4 acc[4] = {{0,0,0,0},{0,0,0,0},{0,0,0,0},{0,0,0,0}};

#pragma unroll 6
    for (int ks = 0; ks < Hdim; ks += 32) {
        bf16x8 a = *(const bf16x8*)(Ap + ks);
#pragma unroll
        for (int n = 0; n < 4; ++n) {
            bf16x8 bb = *(const bf16x8*)(Bp + (size_t)n * 16 * Hdim + ks);
            acc[n] = __builtin_amdgcn_mfma_f32_16x16x32_bf16(a, bb, acc[n], 0, 0, 0);
        }
    }

    // epilogue: tanh+bias -> LDS h-tile [i_local][b]
    __shared__ float hs[64][65];
#pragma unroll
    for (int n = 0; n < 4; ++n) {
        int bb = n * 16 + col;
#pragma unroll
        for (int r = 0; r < 4; ++r) {
            int il = wv * 16 + q * 4 + r;
            hs[il][bb] = tanhf(acc[n][r] + db[i0 + il]);
        }
    }
    __syncthreads();

    // classifier partial: out[b][c] += sum_il cW[c][i0+il]*h[il][b]
    for (int c = wv; c < nlab; c += 4) {
        const float* wr = cW + (size_t)c * Hdim + i0;
        float a = 0.f;
#pragma unroll 16
        for (int il = 0; il < 64; ++il)
            a += wr[il] * hs[il][lane];
        atomicAdd(&out[off + lane * nlab + c], a);
    }
}

extern "C" void kernel_launch(void* const* d_in, const int* in_sizes, int n_in,
                              void* d_out, int out_size, void* d_ws, size_t ws_size,
                              hipStream_t stream) {
    const float* seq  = (const float*)d_in[0];
    const int*   idxr = (const int*)d_in[1];
    const int*   lenr = (const int*)d_in[2];
    const int*   idxn = (const int*)d_in[3];
    const int*   lenn = (const int*)d_in[4];
    const int*   idxd = (const int*)d_in[5];
    const int*   lend = (const int*)d_in[6];
    const float* dWr  = (const float*)d_in[7];
    const float* dbr  = (const float*)d_in[8];
    const float* cWr  = (const float*)d_in[9];
    const float* cbr  = (const float*)d_in[10];
    const float* dWn  = (const float*)d_in[11];
    const float* dbn  = (const float*)d_in[12];
    const float* cWn  = (const float*)d_in[13];
    const float* cbn  = (const float*)d_in[14];
    const float* dWd  = (const float*)d_in[15];
    const float* dbd  = (const float*)d_in[16];
    const float* cWd  = (const float*)d_in[17];
    const float* cbd  = (const float*)d_in[18];
    float* out = (float*)d_out;

    unsigned short* Wbf = (unsigned short*)d_ws;            // 3*768*768 bf16
    unsigned short* Pbf = Wbf + (size_t)3 * Hdim * Hdim;    // 3*64*768  bf16

    k_pool<<<dim3(Bdim, 3), 1024, 0, stream>>>(
        seq, idxr, lenr, idxn, lenn, idxd, lend,
        cbr, cbn, cbd, dWr, dWn, dWd, Wbf, Pbf, out);
    k_dense_cls<<<dim3(Hdim / 64, 3), 256, 0, stream>>>(
        Wbf, Pbf, dbr, dbn, dbd, cWr, cWn, cWd, out);
}

// Round 9
// 189.033 us; speedup vs baseline: 1.0273x; 1.0161x over previous
//
#include <hip/hip_runtime.h>
#include <math.h>

// BioREDirect, 2-kernel (best-of-breed of R5 + R8 lessons).
// K1 (1024 thr, 192 blocks): attention-pool; each wave owns <=4 j's with
//     WAVE-UNIFORM predicated loads (only j<len rows fetched — no traffic
//     doubling), all loads issued together (no serial HBM round-trips, no
//     online-rescale chain). Writes pooled f32. b==0 blocks bias-init out[].
// K2 (256 thr, 36 blocks): R5's proven MFMA dense+tanh (LDS staging + inline
//     f2bf) + fused classifier partials atomicAdd'ed into out.
// NOTE: ~150us of the timed iteration is harness restore/poison fills (fixed):
//     402 MB ws-poison fill ~60us + 151 MB input restore copy ~60us + gaps.

#define Hdim 768
#define Kdim 64
#define Sdim 512
#define Bdim 64
#define LDK  72   // 64 + 8 pad (bf16 units); keeps b128 16B-aligned, banks even

typedef float f32x4 __attribute__((ext_vector_type(4)));
typedef short bf16x8 __attribute__((ext_vector_type(8)));

__device__ __forceinline__ unsigned short f2bf(float f) {
    union { float f; unsigned int u; } c; c.f = f;
    unsigned int u = c.u + 0x7FFFu + ((c.u >> 16) & 1u);  // RNE
    return (unsigned short)(u >> 16);
}

// ---------------- K1: attention pooling, predicated-unrolled j ----------------
__global__ __launch_bounds__(1024) void k_pool(
    const float* __restrict__ seq,
    const int* __restrict__ idxr, const int* __restrict__ lenr,
    const int* __restrict__ idxn, const int* __restrict__ lenn,
    const int* __restrict__ idxd, const int* __restrict__ lend,
    const float* __restrict__ cbr, const float* __restrict__ cbn,
    const float* __restrict__ cbd,
    float* __restrict__ pooled,   // [3][64][768] f32
    float* __restrict__ out)      // bias-init; K2 atomicAdds partials
{
    const int b = blockIdx.x, g = blockIdx.y;
    const int tid = threadIdx.x, lane = tid & 63, wave = tid >> 6;  // 16 waves

    const int* idxp = (g == 0) ? idxr : (g == 1) ? idxn : idxd;
    const int* lnp  = (g == 0) ? lenr : (g == 1) ? lenn : lend;

    __shared__ int   sidx[Kdim];
    __shared__ float wm[16], wl[16], coef[16];
    __shared__ float wpart[16][Hdim];   // 48 KB

    if (tid < Kdim) sidx[tid] = idxp[b * Kdim + tid];
    const int len = lnp[b];

    if (b == 0) {  // bias-init of out (stream-ordered before K2's atomics)
        if (g == 0)      { if (tid < 576) out[tid]       = cbr[tid % 9]; }
        else if (g == 1) { if (tid < 192) out[576 + tid] = cbn[tid % 3]; }
        else             { if (tid < 192) out[768 + tid] = cbd[tid % 3]; }
    }
    __syncthreads();

    float* dst = pooled + ((size_t)g * Bdim + b) * Hdim;

    if (len > 0) {
        const float* row0 = seq + ((size_t)b * Sdim + sidx[0]) * Hdim;
        float g0[12];
#pragma unroll
        for (int k = 0; k < 3; ++k) {
            float4 t = *(const float4*)(row0 + 4 * lane + 256 * k);
            g0[4 * k + 0] = t.x; g0[4 * k + 1] = t.y;
            g0[4 * k + 2] = t.z; g0[4 * k + 3] = t.w;
        }

        // <=4 rows per wave; loads predicated WAVE-UNIFORMLY (j<len), all
        // issued together. v zero-init so masked t contributes exact 0.
        float v[4][12];
#pragma unroll
        for (int t = 0; t < 4; ++t)
#pragma unroll
            for (int k = 0; k < 12; ++k) v[t][k] = 0.f;

#pragma unroll
        for (int t = 0; t < 4; ++t) {
            int j = wave + 16 * t;
            if (j < len) {   // wave-uniform: s_cbranch, no divergence
                const float* rowj = seq + ((size_t)b * Sdim + sidx[j]) * Hdim + 4 * lane;
#pragma unroll
                for (int k = 0; k < 3; ++k) {
                    float4 x = *(const float4*)(rowj + 256 * k);
                    v[t][4 * k + 0] = x.x; v[t][4 * k + 1] = x.y;
                    v[t][4 * k + 2] = x.z; v[t][4 * k + 3] = x.w;
                }
            }
        }

        float s[4];
#pragma unroll
        for (int t = 0; t < 4; ++t) {
            float a = 0.f;
#pragma unroll
            for (int k = 0; k < 12; ++k) a += g0[k] * v[t][k];
            s[t] = a;
        }
        // interleaved butterflies: 4-way ILP on the shuffle chain
#pragma unroll
        for (int off = 32; off > 0; off >>= 1)
#pragma unroll
            for (int t = 0; t < 4; ++t) s[t] += __shfl_xor(s[t], off, 64);

#pragma unroll
        for (int t = 0; t < 4; ++t)
            if (wave + 16 * t >= len) s[t] = -1e30f;

        float m = fmaxf(fmaxf(s[0], s[1]), fmaxf(s[2], s[3]));
        float e[4], l = 0.f;
#pragma unroll
        for (int t = 0; t < 4; ++t) {
            e[t] = (wave + 16 * t < len) ? __expf(s[t] - m) : 0.f;
            l += e[t];
        }
        float p[12];
#pragma unroll
        for (int k = 0; k < 12; ++k)
            p[k] = e[0] * v[0][k] + e[1] * v[1][k] + e[2] * v[2][k] + e[3] * v[3][k];

        if (lane == 0) { wm[wave] = m; wl[wave] = l; }
#pragma unroll
        for (int k = 0; k < 3; ++k)
            *(float4*)&wpart[wave][4 * lane + 256 * k] =
                make_float4(p[4 * k], p[4 * k + 1], p[4 * k + 2], p[4 * k + 3]);
        __syncthreads();

        if (wave == 0 && lane < 16) {
            float mw = wm[lane], lw = wl[lane];
            float M = mw;
#pragma unroll
            for (int off = 8; off > 0; off >>= 1) M = fmaxf(M, __shfl_xor(M, off, 64));
            float sc = __expf(mw - M);        // 0 for waves with no j (mw=-1e30)
            float Ls = lw * sc;
#pragma unroll
            for (int off = 8; off > 0; off >>= 1) Ls += __shfl_xor(Ls, off, 64);
            coef[lane] = sc / Ls;
        }
        __syncthreads();

        if (tid < Hdim) {
            float acc = 0.f;
#pragma unroll
            for (int w = 0; w < 16; ++w) acc += wpart[w][tid] * coef[w];
            dst[tid] = acc;
        }
    } else {
        if (tid < Hdim) dst[tid] = seq[(size_t)b * Sdim * Hdim + tid];
    }
}

// ---------------- K2: dense+tanh (bf16 MFMA, LDS-staged) + classifier ----------------
__global__ __launch_bounds__(256) void k_dense_cls(
    const float* __restrict__ pooled,   // [3][64][768]
    const float* __restrict__ dWr, const float* __restrict__ dbr,
    const float* __restrict__ cWr,
    const float* __restrict__ dWn, const float* __restrict__ dbn,
    const float* __restrict__ cWn,
    const float* __restrict__ dWd, const float* __restrict__ dbd,
    const float* __restrict__ cWd,
    float* __restrict__ out)
{
    const int mt = blockIdx.x, g = blockIdx.y;
    const float *dW, *db, *cW; int nlab, off;
    if (g == 0)      { dW = dWr; db = dbr; cW = cWr; nlab = 9; off = 0;   }
    else if (g == 1) { dW = dWn; db = dbn; cW = cWn; nlab = 3; off = 576; }
    else             { dW = dWd; db = dbd; cW = cWd; nlab = 3; off = 768; }
    const int i0 = mt * 64;

    const int tid = threadIdx.x, lane = tid & 63, wv = tid >> 6;
    const int q = lane >> 4, col = lane & 15;

    __shared__ unsigned short Ws[64 * LDK];
    __shared__ unsigned short Ps[64 * LDK];
    __shared__ float hs[64][65];

    f32x4 acc[4] = {{0,0,0,0},{0,0,0,0},{0,0,0,0},{0,0,0,0}};

    const int srow  = tid >> 2;        // 0..63
    const int cbase = (tid & 3) * 16;  // 0,16,32,48
    const float* Pg = pooled + (size_t)g * Bdim * Hdim;

    for (int kk = 0; kk < Hdim; kk += 64) {
#pragma unroll
        for (int u = 0; u < 4; ++u) {
            int c = cbase + 4 * u;
            float4 w4 = *(const float4*)(dW + (size_t)(i0 + srow) * Hdim + kk + c);
            float4 p4 = *(const float4*)(Pg + (size_t)srow * Hdim + kk + c);
            *(ushort4*)&Ws[srow * LDK + c] = make_ushort4(f2bf(w4.x), f2bf(w4.y), f2bf(w4.z), f2bf(w4.w));
            *(ushort4*)&Ps[srow * LDK + c] = make_ushort4(f2bf(p4.x), f2bf(p4.y), f2bf(p4.z), f2bf(p4.w));
        }
        __syncthreads();
#pragma unroll
        for (int ks = 0; ks < 64; ks += 32) {
            bf16x8 a = *(const bf16x8*)&Ws[(wv * 16 + col) * LDK + ks + 8 * q];
#pragma unroll
            for (int n = 0; n < 4; ++n) {
                bf16x8 bb = *(const bf16x8*)&Ps[(n * 16 + col) * LDK + ks + 8 * q];
                acc[n] = __builtin_amdgcn_mfma_f32_16x16x32_bf16(a, bb, acc[n], 0, 0, 0);
            }
        }
        __syncthreads();
    }

    // epilogue: tanh+bias -> LDS h-tile [i_local][b]
#pragma unroll
    for (int n = 0; n < 4; ++n) {
        int bb = n * 16 + col;
#pragma unroll
        for (int r = 0; r < 4; ++r) {
            int il = wv * 16 + q * 4 + r;
            hs[il][bb] = tanhf(acc[n][r] + db[i0 + il]);
        }
    }
    __syncthreads();

    // classifier partial: out[b][c] += sum_il cW[c][i0+il]*h[il][b]
    for (int c = wv; c < nlab; c += 4) {
        const float* wr = cW + (size_t)c * Hdim + i0;
        float a = 0.f;
#pragma unroll 16
        for (int il = 0; il < 64; ++il)
            a += wr[il] * hs[il][lane];
        atomicAdd(&out[off + lane * nlab + c], a);
    }
}

extern "C" void kernel_launch(void* const* d_in, const int* in_sizes, int n_in,
                              void* d_out, int out_size, void* d_ws, size_t ws_size,
                              hipStream_t stream) {
    const float* seq  = (const float*)d_in[0];
    const int*   idxr = (const int*)d_in[1];
    const int*   lenr = (const int*)d_in[2];
    const int*   idxn = (const int*)d_in[3];
    const int*   lenn = (const int*)d_in[4];
    const int*   idxd = (const int*)d_in[5];
    const int*   lend = (const int*)d_in[6];
    const float* dWr  = (const float*)d_in[7];
    const float* dbr  = (const float*)d_in[8];
    const float* cWr  = (const float*)d_in[9];
    const float* cbr  = (const float*)d_in[10];
    const float* dWn  = (const float*)d_in[11];
    const float* dbn  = (const float*)d_in[12];
    const float* cWn  = (const float*)d_in[13];
    const float* cbn  = (const float*)d_in[14];
    const float* dWd  = (const float*)d_in[15];
    const float* dbd  = (const float*)d_in[16];
    const float* cWd  = (const float*)d_in[17];
    const float* cbd  = (const float*)d_in[18];
    float* out = (float*)d_out;

    float* pooled = (float*)d_ws;   // 3*64*768 f32

    k_pool<<<dim3(Bdim, 3), 1024, 0, stream>>>(
        seq, idxr, lenr, idxn, lenn, idxd, lend, cbr, cbn, cbd, pooled, out);
    k_dense_cls<<<dim3(Hdim / 64, 3), 256, 0, stream>>>(
        pooled, dWr, dbr, cWr, dWn, dbn, cWn, dWd, dbd, cWd, out);
}